// Round 2
// baseline (711.589 us; speedup 1.0000x reference)
//
#include <hip/hip_runtime.h>
#include <cstdint>
#include <cmath>

typedef short s16x8 __attribute__((ext_vector_type(8)));
typedef float f32x4 __attribute__((ext_vector_type(4)));
typedef int   i32x4 __attribute__((ext_vector_type(4)));
typedef unsigned short u16;

#define E_DIM 2048
#define SEQ   2048
#define NB    2
#define NH    16
#define HD    128
#define BS_TOT 4096   // NB*SEQ

__device__ __forceinline__ u16 f2bf(float f) {
  unsigned u = __float_as_uint(f);
  u += 0x7fffu + ((u >> 16) & 1u);
  return (u16)(u >> 16);
}
__device__ __forceinline__ float bf2f(u16 h) {
  return __uint_as_float(((unsigned)h) << 16);
}
__device__ __forceinline__ float rmax16(float v) {
  v = fmaxf(v, __shfl_xor(v, 1));
  v = fmaxf(v, __shfl_xor(v, 2));
  v = fmaxf(v, __shfl_xor(v, 4));
  v = fmaxf(v, __shfl_xor(v, 8));
  return v;
}
__device__ __forceinline__ float rsum16(float v) {
  v += __shfl_xor(v, 1);
  v += __shfl_xor(v, 2);
  v += __shfl_xor(v, 4);
  v += __shfl_xor(v, 8);
  return v;
}

// ---------------- cast fp32 -> bf16, 8 elements/thread ----------------
__global__ __launch_bounds__(256) void cast_kernel(const float* __restrict__ in,
                                                   u16* __restrict__ out) {
  const size_t t = (size_t)blockIdx.x * 256 + threadIdx.x;
  const float* p = in + t * 8;
  f32x4 a = *(const f32x4*)p;
  f32x4 b = *(const f32x4*)(p + 4);
  union { u16 u[8]; i32x4 v; } r;
  r.u[0] = f2bf(a[0]); r.u[1] = f2bf(a[1]); r.u[2] = f2bf(a[2]); r.u[3] = f2bf(a[3]);
  r.u[4] = f2bf(b[0]); r.u[5] = f2bf(b[1]); r.u[6] = f2bf(b[2]); r.u[7] = f2bf(b[3]);
  *(i32x4*)(out + t * 8) = r.v;
}

// ---------------- NT GEMM: C[M,N] = A[M,K] * B[N,K]^T ----------------
// CVTA/CVTB: operand is fp32 in global, converted to bf16 during LDS staging.
// 128x128 tile, BK=32, 256 threads (4 waves), each wave 64x64 via 4x4 16x16x32 MFMA.
template <typename OT, bool CVTA, bool CVTB>
__global__ __launch_bounds__(256) void gemm_nt(const void* __restrict__ Av,
                                               const void* __restrict__ Bv,
                                               OT* __restrict__ C,
                                               int M, int N, int K) {
  __shared__ u16 As[128 * 40];   // stride 40 elems (+8 pad) -> 2-way LDS conflicts only
  __shared__ u16 Bs[128 * 40];
  const int t  = threadIdx.x;
  const int w  = t >> 6, l = t & 63, lq = l >> 4, lm = l & 15;
  const int wr = w >> 1, wc = w & 1;
  const int m0 = blockIdx.y * 128, n0 = blockIdx.x * 128;

  const f32x4 fzero = {0.f, 0.f, 0.f, 0.f};
  f32x4 acc[4][4];
#pragma unroll
  for (int mi = 0; mi < 4; ++mi)
#pragma unroll
    for (int ni = 0; ni < 4; ++ni) acc[mi][ni] = fzero;

  for (int k0 = 0; k0 < K; k0 += 32) {
    __syncthreads();
    // stage A
    if constexpr (CVTA) {
      const float* A = (const float*)Av;
#pragma unroll
      for (int i = 0; i < 2; ++i) {
        const int ci = i * 256 + t;
        const int r = ci >> 2, kc = ci & 3;
        const float* s = A + (size_t)(m0 + r) * K + k0 + kc * 8;
        f32x4 a = *(const f32x4*)s;
        f32x4 b = *(const f32x4*)(s + 4);
        union { u16 u[8]; i32x4 v; } rr;
        rr.u[0] = f2bf(a[0]); rr.u[1] = f2bf(a[1]); rr.u[2] = f2bf(a[2]); rr.u[3] = f2bf(a[3]);
        rr.u[4] = f2bf(b[0]); rr.u[5] = f2bf(b[1]); rr.u[6] = f2bf(b[2]); rr.u[7] = f2bf(b[3]);
        *(i32x4*)(As + r * 40 + kc * 8) = rr.v;
      }
    } else {
      const u16* A = (const u16*)Av;
#pragma unroll
      for (int i = 0; i < 2; ++i) {
        const int ci = i * 256 + t;
        const int r = ci >> 2, kc = ci & 3;
        *(i32x4*)(As + r * 40 + kc * 8) =
            *(const i32x4*)(A + (size_t)(m0 + r) * K + k0 + kc * 8);
      }
    }
    // stage B
    if constexpr (CVTB) {
      const float* B = (const float*)Bv;
#pragma unroll
      for (int i = 0; i < 2; ++i) {
        const int ci = i * 256 + t;
        const int r = ci >> 2, kc = ci & 3;
        const float* s = B + (size_t)(n0 + r) * K + k0 + kc * 8;
        f32x4 a = *(const f32x4*)s;
        f32x4 b = *(const f32x4*)(s + 4);
        union { u16 u[8]; i32x4 v; } rr;
        rr.u[0] = f2bf(a[0]); rr.u[1] = f2bf(a[1]); rr.u[2] = f2bf(a[2]); rr.u[3] = f2bf(a[3]);
        rr.u[4] = f2bf(b[0]); rr.u[5] = f2bf(b[1]); rr.u[6] = f2bf(b[2]); rr.u[7] = f2bf(b[3]);
        *(i32x4*)(Bs + r * 40 + kc * 8) = rr.v;
      }
    } else {
      const u16* B = (const u16*)Bv;
#pragma unroll
      for (int i = 0; i < 2; ++i) {
        const int ci = i * 256 + t;
        const int r = ci >> 2, kc = ci & 3;
        *(i32x4*)(Bs + r * 40 + kc * 8) =
            *(const i32x4*)(B + (size_t)(n0 + r) * K + k0 + kc * 8);
      }
    }
    __syncthreads();
    s16x8 af[4], bf[4];
#pragma unroll
    for (int mi = 0; mi < 4; ++mi)
      af[mi] = *(const s16x8*)(As + (wr * 64 + mi * 16 + lm) * 40 + lq * 8);
#pragma unroll
    for (int ni = 0; ni < 4; ++ni)
      bf[ni] = *(const s16x8*)(Bs + (wc * 64 + ni * 16 + lm) * 40 + lq * 8);
#pragma unroll
    for (int mi = 0; mi < 4; ++mi)
#pragma unroll
      for (int ni = 0; ni < 4; ++ni)
        acc[mi][ni] = __builtin_amdgcn_mfma_f32_16x16x32_bf16(af[mi], bf[ni], acc[mi][ni], 0, 0, 0);
  }

#pragma unroll
  for (int mi = 0; mi < 4; ++mi)
#pragma unroll
    for (int ni = 0; ni < 4; ++ni)
#pragma unroll
      for (int rr = 0; rr < 4; ++rr) {
        const int row = m0 + wr * 64 + mi * 16 + lq * 4 + rr;
        const int col = n0 + wc * 64 + ni * 16 + lm;
        const float v = acc[mi][ni][rr];
        if constexpr (sizeof(OT) == 2) {
          C[(size_t)row * N + col] = (OT)f2bf(v);
        } else {
          C[(size_t)row * N + col] = v;
        }
      }
}

// ---------------- RoPE (interleaved) on q and k, in place, bf16 ----------------
__global__ __launch_bounds__(256) void rope_kernel(u16* __restrict__ q, u16* __restrict__ k) {
  const size_t t = (size_t)blockIdx.x * 256 + threadIdx.x;
  const size_t e8 = t * 8;
  const int col = (int)(e8 & (E_DIM - 1));
  const int row = (int)(e8 >> 11);
  const int s   = row & (SEQ - 1);
  const int d   = col & (HD - 1);
  float cs[4], sn[4];
#pragma unroll
  for (int j = 0; j < 4; ++j) {
    // inv_freq = 10000^(-2i/128) = exp2(-i * log2(10000)/64)
    const float inv = exp2f(-0.20762050593046014f * (float)((d >> 1) + j));
    const float ang = (float)s * inv;
    sincosf(ang, &sn[j], &cs[j]);
  }
  u16* qp = q + e8;
  u16* kp = k + e8;
  union { u16 u[8]; i32x4 v; } a, b;
  a.v = *(const i32x4*)qp;
  b.v = *(const i32x4*)kp;
#pragma unroll
  for (int j = 0; j < 4; ++j) {
    const float q1 = bf2f(a.u[2 * j]), q2 = bf2f(a.u[2 * j + 1]);
    const float k1 = bf2f(b.u[2 * j]), k2 = bf2f(b.u[2 * j + 1]);
    a.u[2 * j]     = f2bf(q1 * cs[j] - q2 * sn[j]);
    a.u[2 * j + 1] = f2bf(q1 * sn[j] + q2 * cs[j]);
    b.u[2 * j]     = f2bf(k1 * cs[j] - k2 * sn[j]);
    b.u[2 * j + 1] = f2bf(k1 * sn[j] + k2 * cs[j]);
  }
  *(i32x4*)qp = a.v;
  *(i32x4*)kp = b.v;
}

// ---------------- causal flash attention ----------------
// grid: 512 blocks = qt(16) x h(16) x b(2); 256 threads = 4 waves x 32 q-rows.
// LDS: KV (K-tile then V^T-tile, 32KB) + Ps (per-wave P in A-layout, 32KB) = 64KB.
// 16B-chunk XOR swizzle: phys_chunk = chunk ^ (row & 15) -> <=2-way conflicts.
__global__ __launch_bounds__(256) void flash_kernel(const u16* __restrict__ q,
                                                    const u16* __restrict__ kmat,
                                                    const u16* __restrict__ vt,
                                                    u16* __restrict__ attn) {
  __shared__ u16 KV[128 * 128];
  __shared__ u16 Ps[4 * 32 * 128];
  const int bx = blockIdx.x;
  const int qt = bx & 15, h = (bx >> 4) & 15, b = bx >> 8;
  const int t = threadIdx.x, w = t >> 6, l = t & 63, lq = l >> 4, lm = l & 15;

  // Q fragments for this wave's 32 rows, whole D=128, kept in registers.
  const u16* qp = q + (size_t)(b * SEQ + qt * 128 + w * 32) * E_DIM + h * HD;
  s16x8 qf[2][4];
#pragma unroll
  for (int mi = 0; mi < 2; ++mi)
#pragma unroll
    for (int kx = 0; kx < 4; ++kx)
      qf[mi][kx] = *(const s16x8*)(qp + (size_t)(mi * 16 + lm) * E_DIM + kx * 32 + lq * 8);

  const f32x4 fzero = {0.f, 0.f, 0.f, 0.f};
  float m_i[2][4], l_i[2][4];
  f32x4 acc_o[2][8];
#pragma unroll
  for (int mi = 0; mi < 2; ++mi)
#pragma unroll
    for (int rr = 0; rr < 4; ++rr) { m_i[mi][rr] = -1e30f; l_i[mi][rr] = 0.f; }
#pragma unroll
  for (int mi = 0; mi < 2; ++mi)
#pragma unroll
    for (int nd = 0; nd < 8; ++nd) acc_o[mi][nd] = fzero;

  u16* myP = Ps + w * (32 * 128);
  const float sl2 = 0.08838834764831845f * 1.4426950408889634f;  // 1/sqrt(128)*log2(e)

  const int nT = qt + 1;
  for (int it = 0; it < nT; ++it) {
    const int k0 = it * 128;
    __syncthreads();  // KV free (previous PV done)
    {  // stage K tile [key][d] (swizzled)
      const u16* kp = kmat + (size_t)(b * SEQ + k0) * E_DIM + h * HD;
#pragma unroll
      for (int i = 0; i < 8; ++i) {
        const int ci = i * 256 + t;
        const int r = ci >> 4, cc = ci & 15;
        *(i32x4*)(KV + r * 128 + ((cc ^ (r & 15)) << 3)) =
            *(const i32x4*)(kp + (size_t)r * E_DIM + cc * 8);
      }
    }
    __syncthreads();

    // S = Q K^T  (per wave: 32 x 128)
    f32x4 sc[2][8];
#pragma unroll
    for (int mi = 0; mi < 2; ++mi)
#pragma unroll
      for (int ni = 0; ni < 8; ++ni) sc[mi][ni] = fzero;
#pragma unroll
    for (int kx = 0; kx < 4; ++kx) {
      s16x8 bfr[8];
#pragma unroll
      for (int ni = 0; ni < 8; ++ni) {
        const int r = ni * 16 + lm;
        bfr[ni] = *(const s16x8*)(KV + r * 128 + (((kx * 4 + lq) ^ lm) << 3));
      }
#pragma unroll
      for (int ni = 0; ni < 8; ++ni) {
        sc[0][ni] = __builtin_amdgcn_mfma_f32_16x16x32_bf16(qf[0][kx], bfr[ni], sc[0][ni], 0, 0, 0);
        sc[1][ni] = __builtin_amdgcn_mfma_f32_16x16x32_bf16(qf[1][kx], bfr[ni], sc[1][ni], 0, 0, 0);
      }
    }

    // online softmax (exp2 domain)
#pragma unroll
    for (int mi = 0; mi < 2; ++mi)
#pragma unroll
      for (int rr = 0; rr < 4; ++rr) {
        const int qloc = w * 32 + mi * 16 + lq * 4 + rr;
        float mt = -1e30f;
#pragma unroll
        for (int ni = 0; ni < 8; ++ni) {
          float s = sc[mi][ni][rr] * sl2;
          if (it == qt && (ni * 16 + lm) > qloc) s = -1e30f;
          sc[mi][ni][rr] = s;
          mt = fmaxf(mt, s);
        }
        mt = rmax16(mt);
        const float mn = fmaxf(m_i[mi][rr], mt);
        const float al = exp2f(m_i[mi][rr] - mn);
        float rs = 0.f;
#pragma unroll
        for (int ni = 0; ni < 8; ++ni) {
          const float p = exp2f(sc[mi][ni][rr] - mn);
          sc[mi][ni][rr] = p;
          rs += p;
        }
        rs = rsum16(rs);
        l_i[mi][rr] = l_i[mi][rr] * al + rs;
        m_i[mi][rr] = mn;
#pragma unroll
        for (int nd = 0; nd < 8; ++nd) acc_o[mi][nd][rr] *= al;
      }

    // P (bf16) -> per-wave LDS in A-operand layout (swizzled)
#pragma unroll
    for (int mi = 0; mi < 2; ++mi)
#pragma unroll
      for (int rr = 0; rr < 4; ++rr) {
        const int r = mi * 16 + lq * 4 + rr;
        const int swz = r & 15;
#pragma unroll
        for (int ni = 0; ni < 8; ++ni) {
          const int c = ni * 16 + lm;
          myP[r * 128 + (((c >> 3) ^ swz) << 3) + (c & 7)] = f2bf(sc[mi][ni][rr]);
        }
      }

    __syncthreads();  // everyone done reading K from KV
    {  // stage V^T tile [d][key] (swizzled) — vt global is [E][B*S]
      const u16* vp = vt + (size_t)(h * HD) * BS_TOT + b * SEQ + k0;
#pragma unroll
      for (int i = 0; i < 8; ++i) {
        const int ci = i * 256 + t;
        const int r = ci >> 4, cc = ci & 15;
        *(i32x4*)(KV + r * 128 + ((cc ^ (r & 15)) << 3)) =
            *(const i32x4*)(vp + (size_t)r * BS_TOT + cc * 8);
      }
    }
    __syncthreads();

    // O += P V  (K-dim = 128 keys)
#pragma unroll
    for (int kx = 0; kx < 4; ++kx) {
      s16x8 pf[2];
#pragma unroll
      for (int mi = 0; mi < 2; ++mi) {
        const int r = mi * 16 + lm;
        pf[mi] = *(const s16x8*)(myP + r * 128 + (((kx * 4 + lq) ^ lm) << 3));
      }
#pragma unroll
      for (int nd = 0; nd < 8; ++nd) {
        const int r = nd * 16 + lm;
        const s16x8 vf = *(const s16x8*)(KV + r * 128 + (((kx * 4 + lq) ^ lm) << 3));
        acc_o[0][nd] = __builtin_amdgcn_mfma_f32_16x16x32_bf16(pf[0], vf, acc_o[0][nd], 0, 0, 0);
        acc_o[1][nd] = __builtin_amdgcn_mfma_f32_16x16x32_bf16(pf[1], vf, acc_o[1][nd], 0, 0, 0);
      }
    }
  }

  // epilogue: normalize and store bf16
  u16* op = attn + (size_t)(b * SEQ + qt * 128 + w * 32) * E_DIM + h * HD;
#pragma unroll
  for (int mi = 0; mi < 2; ++mi)
#pragma unroll
    for (int rr = 0; rr < 4; ++rr) {
      const float inv = 1.0f / l_i[mi][rr];
      const int row = mi * 16 + lq * 4 + rr;
#pragma unroll
      for (int nd = 0; nd < 8; ++nd) {
        const int colc = nd * 16 + lm;
        op[(size_t)row * E_DIM + colc] = f2bf(acc_o[mi][nd][rr] * inv);
      }
    }
}

// ---------------- launch ----------------
// Workspace budget: 32 MiB ONLY (xb 16 MiB + vtb 16 MiB). Q/K live in d_out
// (32 MiB fp32, legal scratch until the final GEMM overwrites it). Round-1
// post-mortem: the old layout assumed 72 MiB of ws and likely overran it,
// corrupting the harness's pristine buffers (first call right, all later
// calls identically wrong).
extern "C" void kernel_launch(void* const* d_in, const int* in_sizes, int n_in,
                              void* d_out, int out_size, void* d_ws, size_t ws_size,
                              hipStream_t stream) {
  const float* x  = (const float*)d_in[0];
  const float* Wq = (const float*)d_in[1];
  const float* Wk = (const float*)d_in[2];
  const float* Wv = (const float*)d_in[3];
  const float* Wo = (const float*)d_in[4];
  float* out = (float*)d_out;
  char* ws = (char*)d_ws;

  u16* xb    = (u16*)(ws);                        // 16 MiB: x bf16, later reused as attn
  u16* vtb   = (u16*)(ws + (size_t)16 * 1048576); // 16 MiB (V^T: [E][B*S])
  u16* qb    = (u16*)d_out;                       // 16 MiB scratch inside d_out
  u16* kb    = (u16*)d_out + (size_t)8 * 1048576; // 16 MiB scratch inside d_out
  u16* attnb = xb;

  (void)in_sizes; (void)n_in; (void)out_size; (void)ws_size;

  cast_kernel<<<4096, 256, 0, stream>>>(x, xb);
  // Q = x Wq^T ; K = x Wk^T  (weights converted fp32->bf16 during LDS staging)
  gemm_nt<u16, false, true><<<dim3(16, 32), 256, 0, stream>>>(xb, Wq, qb, 4096, 2048, 2048);
  gemm_nt<u16, false, true><<<dim3(16, 32), 256, 0, stream>>>(xb, Wk, kb, 4096, 2048, 2048);
  // V^T[e][s] = sum_k Wv[e][k] * x[s][k]  -> same NT kernel, swapped operands
  gemm_nt<u16, true, false><<<dim3(32, 16), 256, 0, stream>>>(Wv, xb, vtb, 2048, 4096, 2048);
  rope_kernel<<<4096, 256, 0, stream>>>(qb, kb);
  flash_kernel<<<512, 256, 0, stream>>>(qb, kb, vtb, attnb);
  // out = attn Wo^T  — fully overwrites d_out (qb/kb scratch is dead now)
  gemm_nt<float, false, true><<<dim3(16, 32), 256, 0, stream>>>(attnb, Wo, out, 4096, 2048, 2048);
}

// Round 3
// 536.563 us; speedup vs baseline: 1.3262x; 1.3262x over previous
//
#include <hip/hip_runtime.h>
#include <cstdint>
#include <cmath>

typedef short s16x8 __attribute__((ext_vector_type(8)));
typedef float f32x4 __attribute__((ext_vector_type(4)));
typedef int   i32x4 __attribute__((ext_vector_type(4)));
typedef unsigned short u16;

#define E_DIM 2048
#define SEQ   2048
#define NB    2
#define NH    16
#define HD    128
#define BS_TOT 4096   // NB*SEQ

__device__ __forceinline__ u16 f2bf(float f) {
  unsigned u = __float_as_uint(f);
  u += 0x7fffu + ((u >> 16) & 1u);
  return (u16)(u >> 16);
}
__device__ __forceinline__ float bf2f(u16 h) {
  return __uint_as_float(((unsigned)h) << 16);
}
__device__ __forceinline__ float rmax16(float v) {
  v = fmaxf(v, __shfl_xor(v, 1));
  v = fmaxf(v, __shfl_xor(v, 2));
  v = fmaxf(v, __shfl_xor(v, 4));
  v = fmaxf(v, __shfl_xor(v, 8));
  return v;
}
__device__ __forceinline__ float rsum16(float v) {
  v += __shfl_xor(v, 1);
  v += __shfl_xor(v, 2);
  v += __shfl_xor(v, 4);
  v += __shfl_xor(v, 8);
  return v;
}

// async global->LDS, 16B per lane. LDS dest is wave-uniform base + lane*16,
// so the per-lane lds ptr MUST be base + lane*16 (we arrange all staging
// loops that way); any swizzle goes into the GLOBAL pointer instead.
__device__ __forceinline__ void gll16(const u16* g, u16* l) {
  __builtin_amdgcn_global_load_lds(
      (const __attribute__((address_space(1))) void*)g,
      (__attribute__((address_space(3))) void*)l, 16, 0, 0);
}

// ---------------- cast fp32 -> bf16, 8 elements/thread ----------------
__global__ __launch_bounds__(256) void cast_kernel(const float* __restrict__ in,
                                                   u16* __restrict__ out) {
  const size_t t = (size_t)blockIdx.x * 256 + threadIdx.x;
  const float* p = in + t * 8;
  f32x4 a = *(const f32x4*)p;
  f32x4 b = *(const f32x4*)(p + 4);
  union { u16 u[8]; i32x4 v; } r;
  r.u[0] = f2bf(a[0]); r.u[1] = f2bf(a[1]); r.u[2] = f2bf(a[2]); r.u[3] = f2bf(a[3]);
  r.u[4] = f2bf(b[0]); r.u[5] = f2bf(b[1]); r.u[6] = f2bf(b[2]); r.u[7] = f2bf(b[3]);
  *(i32x4*)(out + t * 8) = r.v;
}

// ---------------- NT GEMM: C[M,N] = A[M,K] * B[N,K]^T ----------------
// m97 structure: 128x128 tile, BK=32, unpadded 128x32 LDS tiles staged with
// global_load_lds (16B). Chunk swizzle (p_phys = p ^ (r&3)) applied via the
// global pointer. B is always bf16; A is bf16 unless CVTA (fp32 converted
// during VGPR staging — only the Wv GEMM).
template <typename OT, bool CVTA>
__global__ __launch_bounds__(256) void gemm_nt(const void* __restrict__ Av,
                                               const u16* __restrict__ B,
                                               OT* __restrict__ C,
                                               int M, int N, int K) {
  __shared__ __align__(16) u16 As[128 * 32];
  __shared__ __align__(16) u16 Bs[128 * 32];
  const int t  = threadIdx.x;
  const int w  = t >> 6, l = t & 63, lq = l >> 4, lm = l & 15;
  const int wr = w >> 1, wc = w & 1;
  const int m0 = blockIdx.y * 128, n0 = blockIdx.x * 128;

  const f32x4 fzero = {0.f, 0.f, 0.f, 0.f};
  f32x4 acc[4][4];
#pragma unroll
  for (int mi = 0; mi < 4; ++mi)
#pragma unroll
    for (int ni = 0; ni < 4; ++ni) acc[mi][ni] = fzero;

  for (int k0 = 0; k0 < K; k0 += 32) {
    __syncthreads();
    if constexpr (CVTA) {
      const float* A = (const float*)Av;
#pragma unroll
      for (int i = 0; i < 2; ++i) {
        const int ci = i * 256 + t;
        const int r = ci >> 2, p = ci & 3, gq = p ^ (r & 3);
        const float* s = A + (size_t)(m0 + r) * K + k0 + gq * 8;
        f32x4 a = *(const f32x4*)s;
        f32x4 b = *(const f32x4*)(s + 4);
        union { u16 u[8]; i32x4 v; } rr;
        rr.u[0] = f2bf(a[0]); rr.u[1] = f2bf(a[1]); rr.u[2] = f2bf(a[2]); rr.u[3] = f2bf(a[3]);
        rr.u[4] = f2bf(b[0]); rr.u[5] = f2bf(b[1]); rr.u[6] = f2bf(b[2]); rr.u[7] = f2bf(b[3]);
        *(i32x4*)(As + ci * 8) = rr.v;
      }
    } else {
      const u16* A = (const u16*)Av;
#pragma unroll
      for (int i = 0; i < 2; ++i) {
        const int ci = i * 256 + t;
        const int r = ci >> 2, p = ci & 3, gq = p ^ (r & 3);
        gll16(A + (size_t)(m0 + r) * K + k0 + gq * 8, As + ci * 8);
      }
    }
#pragma unroll
    for (int i = 0; i < 2; ++i) {
      const int ci = i * 256 + t;
      const int r = ci >> 2, p = ci & 3, gq = p ^ (r & 3);
      gll16(B + (size_t)(n0 + r) * K + k0 + gq * 8, Bs + ci * 8);
    }
    __syncthreads();
    s16x8 af[4], bf[4];
#pragma unroll
    for (int mi = 0; mi < 4; ++mi) {
      const int ra = wr * 64 + mi * 16 + lm;
      af[mi] = *(const s16x8*)(As + ra * 32 + ((lq ^ (ra & 3)) << 3));
    }
#pragma unroll
    for (int ni = 0; ni < 4; ++ni) {
      const int rb = wc * 64 + ni * 16 + lm;
      bf[ni] = *(const s16x8*)(Bs + rb * 32 + ((lq ^ (rb & 3)) << 3));
    }
#pragma unroll
    for (int mi = 0; mi < 4; ++mi)
#pragma unroll
      for (int ni = 0; ni < 4; ++ni)
        acc[mi][ni] = __builtin_amdgcn_mfma_f32_16x16x32_bf16(af[mi], bf[ni], acc[mi][ni], 0, 0, 0);
  }

#pragma unroll
  for (int mi = 0; mi < 4; ++mi)
#pragma unroll
    for (int ni = 0; ni < 4; ++ni)
#pragma unroll
      for (int rr = 0; rr < 4; ++rr) {
        const int row = m0 + wr * 64 + mi * 16 + lq * 4 + rr;
        const int col = n0 + wc * 64 + ni * 16 + lm;
        const float v = acc[mi][ni][rr];
        if constexpr (sizeof(OT) == 2) {
          C[(size_t)row * N + col] = (OT)f2bf(v);
        } else {
          C[(size_t)row * N + col] = v;
        }
      }
}

// ---------------- RoPE (interleaved) on q and k, in place, bf16 ----------------
__global__ __launch_bounds__(256) void rope_kernel(u16* __restrict__ q, u16* __restrict__ k) {
  const size_t t = (size_t)blockIdx.x * 256 + threadIdx.x;
  const size_t e8 = t * 8;
  const int col = (int)(e8 & (E_DIM - 1));
  const int row = (int)(e8 >> 11);
  const int s   = row & (SEQ - 1);
  const int d   = col & (HD - 1);
  float cs[4], sn[4];
#pragma unroll
  for (int j = 0; j < 4; ++j) {
    const float inv = exp2f(-0.20762050593046014f * (float)((d >> 1) + j));
    const float ang = (float)s * inv;
    sincosf(ang, &sn[j], &cs[j]);
  }
  u16* qp = q + e8;
  u16* kp = k + e8;
  union { u16 u[8]; i32x4 v; } a, b;
  a.v = *(const i32x4*)qp;
  b.v = *(const i32x4*)kp;
#pragma unroll
  for (int j = 0; j < 4; ++j) {
    const float q1 = bf2f(a.u[2 * j]), q2 = bf2f(a.u[2 * j + 1]);
    const float k1 = bf2f(b.u[2 * j]), k2 = bf2f(b.u[2 * j + 1]);
    a.u[2 * j]     = f2bf(q1 * cs[j] - q2 * sn[j]);
    a.u[2 * j + 1] = f2bf(q1 * sn[j] + q2 * cs[j]);
    b.u[2 * j]     = f2bf(k1 * cs[j] - k2 * sn[j]);
    b.u[2 * j + 1] = f2bf(k1 * sn[j] + k2 * cs[j]);
  }
  *(i32x4*)qp = a.v;
  *(i32x4*)kp = b.v;
}

// ---------------- causal flash attention v2 ----------------
// 64 q-rows/block, 4 waves x 16 rows. Grid 1024 = qt(32) x h(16) x b(2),
// heavy-first (qt = 31-(bx&31)) so 16-tile blocks start immediately; the
// 2-blocks/CU residency (64 KiB LDS) backfills from the 4-blocks/CU of work.
// LDS: K [0,16K) elems | V [16K,32K) elems; P overlays K after sync3.
// 3 barriers/tile; K+V staged together via global_load_lds (swizzled gptr)
// so V-load latency hides under QK^T+softmax.
__global__ __launch_bounds__(256, 2) void flash_kernel(const u16* __restrict__ q,
                                                       const u16* __restrict__ kmat,
                                                       const u16* __restrict__ vt,
                                                       u16* __restrict__ attn) {
  __shared__ __align__(16) u16 KV[32768];  // 64 KiB
  const int bx = blockIdx.x;
  const int qt = 31 - (bx & 31), h = (bx >> 5) & 15, b = bx >> 9;
  const int t = threadIdx.x, w = t >> 6, l = t & 63, lq = l >> 4, lm = l & 15;
  const int q0 = qt * 64;

  // Q fragments: wave w owns rows q0 + w*16 + [0,16); A-frag m=lm, k=kx*32+lq*8
  const u16* qp = q + (size_t)(b * SEQ + q0 + w * 16) * E_DIM + h * HD;
  s16x8 qf[4];
#pragma unroll
  for (int kx = 0; kx < 4; ++kx)
    qf[kx] = *(const s16x8*)(qp + (size_t)lm * E_DIM + kx * 32 + lq * 8);

  const f32x4 fzero = {0.f, 0.f, 0.f, 0.f};
  float m_i[4], l_i[4];
  f32x4 acc_o[8];
#pragma unroll
  for (int rr = 0; rr < 4; ++rr) { m_i[rr] = -1e30f; l_i[rr] = 0.f; }
#pragma unroll
  for (int nd = 0; nd < 8; ++nd) acc_o[nd] = fzero;

  u16* myP = KV + w * 2048;  // 16x128 bf16, inside the (dead) K region
  const float sl2 = 0.08838834764831845f * 1.4426950408889634f;  // rsqrt(128)*log2(e)

  const u16* kbase = kmat + (size_t)(b * SEQ) * E_DIM + h * HD;
  const u16* vbase = vt + (size_t)(h * HD) * BS_TOT + (size_t)b * SEQ;

  const int nT = (qt >> 1) + 1;
  for (int it = 0; it < nT; ++it) {
    const int k0 = it * 128;
    __syncthreads();  // prev tile's PV done: K/P and V regions free
    // stage K tile [key][d] and V^T tile [d][key], both swizzled via gptr
#pragma unroll
    for (int i = 0; i < 8; ++i) {
      const int ci = i * 256 + t;
      const int r = ci >> 4, gq = (ci & 15) ^ (r & 15);
      gll16(kbase + (size_t)(k0 + r) * E_DIM + gq * 8, KV + ci * 8);
    }
#pragma unroll
    for (int i = 0; i < 8; ++i) {
      const int ci = i * 256 + t;
      const int r = ci >> 4, gq = (ci & 15) ^ (r & 15);
      gll16(vbase + (size_t)r * BS_TOT + k0 + gq * 8, KV + 16384 + ci * 8);
    }
    __syncthreads();  // K and V visible

    // S = Q K^T  (per wave: 16 x 128)
    f32x4 sc[8];
#pragma unroll
    for (int ni = 0; ni < 8; ++ni) sc[ni] = fzero;
#pragma unroll
    for (int kx = 0; kx < 4; ++kx) {
      s16x8 kf[8];
#pragma unroll
      for (int ni = 0; ni < 8; ++ni) {
        const int rn = ni * 16 + lm;
        kf[ni] = *(const s16x8*)(KV + rn * 128 + (((kx * 4 + lq) ^ lm) << 3));
      }
#pragma unroll
      for (int ni = 0; ni < 8; ++ni)
        sc[ni] = __builtin_amdgcn_mfma_f32_16x16x32_bf16(qf[kx], kf[ni], sc[ni], 0, 0, 0);
    }

    // online softmax (exp2 domain)
    const bool diag = (it == nT - 1);
#pragma unroll
    for (int rr = 0; rr < 4; ++rr) {
      const int qrow = q0 + w * 16 + lq * 4 + rr;
      float mt = -1e30f;
#pragma unroll
      for (int ni = 0; ni < 8; ++ni) {
        float s = sc[ni][rr] * sl2;
        if (diag && (k0 + ni * 16 + lm) > qrow) s = -1e30f;
        sc[ni][rr] = s;
        mt = fmaxf(mt, s);
      }
      mt = rmax16(mt);
      const float mn = fmaxf(m_i[rr], mt);
      const float al = exp2f(m_i[rr] - mn);
      float rs = 0.f;
#pragma unroll
      for (int ni = 0; ni < 8; ++ni) {
        const float p = exp2f(sc[ni][rr] - mn);
        sc[ni][rr] = p;
        rs += p;
      }
      rs = rsum16(rs);
      l_i[rr] = l_i[rr] * al + rs;
      m_i[rr] = mn;
#pragma unroll
      for (int nd = 0; nd < 8; ++nd) acc_o[nd][rr] *= al;
    }

    __syncthreads();  // all waves done reading K -> safe to overlay P
    // P (bf16) -> per-wave LDS slice in A-operand layout (swizzled)
#pragma unroll
    for (int rr = 0; rr < 4; ++rr) {
      const int r = lq * 4 + rr;
#pragma unroll
      for (int ni = 0; ni < 8; ++ni) {
        const int c = ni * 16 + lm;
        myP[r * 128 + (((c >> 3) ^ r) << 3) + (c & 7)] = f2bf(sc[ni][rr]);
      }
    }

    // O += P V  (own-wave P slice: no barrier needed, lgkmcnt ordering)
#pragma unroll
    for (int kx = 0; kx < 4; ++kx) {
      const s16x8 pf = *(const s16x8*)(myP + lm * 128 + (((kx * 4 + lq) ^ lm) << 3));
#pragma unroll
      for (int nd = 0; nd < 8; ++nd) {
        const int rn = nd * 16 + lm;
        const s16x8 vf = *(const s16x8*)(KV + 16384 + rn * 128 + (((kx * 4 + lq) ^ lm) << 3));
        acc_o[nd] = __builtin_amdgcn_mfma_f32_16x16x32_bf16(pf, vf, acc_o[nd], 0, 0, 0);
      }
    }
  }

  // epilogue: normalize and store bf16
  u16* op = attn + (size_t)(b * SEQ + q0 + w * 16) * E_DIM + h * HD;
#pragma unroll
  for (int rr = 0; rr < 4; ++rr) {
    const float inv = 1.0f / l_i[rr];
    const int row = lq * 4 + rr;
#pragma unroll
    for (int nd = 0; nd < 8; ++nd) {
      const int colc = nd * 16 + lm;
      op[(size_t)row * E_DIM + colc] = f2bf(acc_o[nd][rr] * inv);
    }
  }
}

// ---------------- launch ----------------
// ws budget 32 MiB: xb @0 (16M, reused as attn), vtb @16M (16M).
// d_out scratch: qb @0, kb @+16M. Weight bf16 copies rotate through dead
// regions: Wq -> kb region (dead until GEMM2 writes it), Wk -> vtb slot
// (dead until GEMM3 writes it), Wo -> vtb slot (dead after flash).
extern "C" void kernel_launch(void* const* d_in, const int* in_sizes, int n_in,
                              void* d_out, int out_size, void* d_ws, size_t ws_size,
                              hipStream_t stream) {
  const float* x  = (const float*)d_in[0];
  const float* Wq = (const float*)d_in[1];
  const float* Wk = (const float*)d_in[2];
  const float* Wv = (const float*)d_in[3];
  const float* Wo = (const float*)d_in[4];
  float* out = (float*)d_out;
  char* ws = (char*)d_ws;

  u16* xb    = (u16*)(ws);                        // 16 MiB
  u16* vtb   = (u16*)(ws + (size_t)16 * 1048576); // 16 MiB (V^T: [E][B*S])
  u16* qb    = (u16*)d_out;                       // 16 MiB scratch in d_out
  u16* kb    = (u16*)d_out + (size_t)8 * 1048576; // 16 MiB scratch in d_out
  u16* wbA   = kb;                                // Wq bf16 (dead before GEMM2)
  u16* wbB   = vtb;                               // Wk / Wo bf16 slot
  u16* attnb = xb;

  (void)in_sizes; (void)n_in; (void)out_size; (void)ws_size;

  cast_kernel<<<4096, 256, 0, stream>>>(x, xb);
  cast_kernel<<<2048, 256, 0, stream>>>(Wq, wbA);
  gemm_nt<u16, false><<<dim3(16, 32), 256, 0, stream>>>(xb, wbA, qb, 4096, 2048, 2048);
  cast_kernel<<<2048, 256, 0, stream>>>(Wk, wbB);
  gemm_nt<u16, false><<<dim3(16, 32), 256, 0, stream>>>(xb, wbB, kb, 4096, 2048, 2048);
  // V^T[e][s] = Wv[e][:] . x[s][:]  (A = Wv fp32 converted on stage, B = xb)
  gemm_nt<u16, true><<<dim3(32, 16), 256, 0, stream>>>(Wv, xb, vtb, 2048, 4096, 2048);
  rope_kernel<<<4096, 256, 0, stream>>>(qb, kb);
  flash_kernel<<<1024, 256, 0, stream>>>(qb, kb, vtb, attnb);
  cast_kernel<<<2048, 256, 0, stream>>>(Wo, wbB);
  gemm_nt<float, false><<<dim3(16, 32), 256, 0, stream>>>(attnb, wbB, out, 4096, 2048, 2048);
}